// Round 7
// baseline (252.552 us; speedup 1.0000x reference)
//
#include <hip/hip_runtime.h>
#include <hip/hip_bf16.h>

// RGCN regression: N=50000, E=800000, R=8, C=H=128.
// Round 7: FUSED aggregation+GEMM. The agg[N,1024] intermediate (102MB write +
// ~64MB re-read per layer, 44% of R6 runtime) is eliminated: with BK=128 each
// K-tile == one relation's slice, so the GEMM block produces its 64x128 A-tile
// in LDS by gathering edges directly from the feature table (L2/L3-resident).
//  - tile kt=0: A = xb rows (root term), staged via global_load_lds
//  - tiles kt=1..8: A = mean_r gathered in regs (4 lanes/node, 32 fp32 each),
//    packed bf16, swizzled ds_write; B staged async under the gather.
// Sort prep (R6), cvt, head unchanged.

constexpr int NN = 50000;
constexpr int EE = 800000;
constexpr int NB = NN * 8;            // 400000 (dst,rel) buckets
constexpr int NCB = (NN + 255) >> 8;  // 196 coarse buckets
constexpr int EPB = 8192;             // edges per partition block
constexpr int PBLK = (EE + EPB - 1) / EPB;   // 98
constexpr int NSB = 2048;             // sub-buckets per coarse bucket

typedef __attribute__((ext_vector_type(8))) short bf16x8;
typedef __attribute__((ext_vector_type(16))) float f32x16;
typedef __attribute__((address_space(3))) uint32_t lds_u32;
typedef __attribute__((address_space(1))) const uint32_t glb_u32;

static __device__ __forceinline__ ushort f2bf(float f) {
    uint u = __float_as_uint(f);
    uint r = (u + 0x7fffu + ((u >> 16) & 1u)) >> 16;   // RTNE
    return (ushort)r;
}
static __device__ __forceinline__ float bflo(uint v) { return __uint_as_float(v << 16); }
static __device__ __forceinline__ float bfhi(uint v) { return __uint_as_float(v & 0xffff0000u); }

static __device__ __forceinline__ void stage16(const void* g, void* lds) {
    __builtin_amdgcn_global_load_lds((glb_u32*)g, (lds_u32*)lds, 16, 0, 0);
}

// ---------------- P1: coarse histogram (dst>>8), LDS-aggregated ----------------
__global__ __launch_bounds__(1024) void chist_kernel(const int* __restrict__ dst,
                                                     int* __restrict__ ghist) {
    __shared__ int h[NCB];
    const int t = threadIdx.x;
    for (int i = t; i < NCB; i += 1024) h[i] = 0;
    __syncthreads();
    const int e0 = blockIdx.x * EPB + t;
#pragma unroll
    for (int jj = 0; jj < 8; ++jj) {
        const int e = e0 + jj * 1024;
        if (e < EE) atomicAdd(&h[dst[e] >> 8], 1);
    }
    __syncthreads();
    for (int i = t; i < NCB; i += 1024)
        if (h[i]) atomicAdd(&ghist[i], h[i]);
}

// ---------------- P2: scan 196 coarse totals ----------------
__global__ __launch_bounds__(256) void cscan_kernel(const int* __restrict__ ghist,
                                                    int* __restrict__ gstart,
                                                    int* __restrict__ gcur) {
    __shared__ int sm[256];
    const int t = threadIdx.x;
    const int v = (t < NCB) ? ghist[t] : 0;
    sm[t] = v;
    __syncthreads();
    for (int d = 1; d < 256; d <<= 1) {
        int u = (t >= d) ? sm[t - d] : 0;
        __syncthreads();
        sm[t] += u;
        __syncthreads();
    }
    const int excl = sm[t] - v;
    if (t < NCB) { gstart[t] = excl; gcur[t] = excl; }
    if (t == NCB - 1) gstart[NCB] = excl + v;   // == EE
}

// ---------------- P3: coarse partition, block-reserved ranges ----------------
// packed = (dlow<<19) | (et<<16) | src
__global__ __launch_bounds__(1024) void cpart_kernel(const int* __restrict__ src,
                                                     const int* __restrict__ dst,
                                                     const int* __restrict__ et,
                                                     int* __restrict__ gcur,
                                                     uint* __restrict__ packed) {
    __shared__ int h[NCB];
    const int t = threadIdx.x;
    for (int i = t; i < NCB; i += 1024) h[i] = 0;
    __syncthreads();
    const int e0 = blockIdx.x * EPB + t;
    int myb[8]; uint mydat[8];
#pragma unroll
    for (int jj = 0; jj < 8; ++jj) {
        const int e = e0 + jj * 1024;
        if (e < EE) {
            const int d = dst[e];
            myb[jj] = d >> 8;
            mydat[jj] = (uint)src[e] | ((uint)et[e] << 16) | ((uint)(d & 255) << 19);
            atomicAdd(&h[myb[jj]], 1);
        } else myb[jj] = -1;
    }
    __syncthreads();
    for (int i = t; i < NCB; i += 1024)
        h[i] = h[i] ? atomicAdd(&gcur[i], h[i]) : 0;   // h becomes running cursor
    __syncthreads();
#pragma unroll
    for (int jj = 0; jj < 8; ++jj) {
        if (myb[jj] >= 0) {
            const int pos = atomicAdd(&h[myb[jj]], 1);
            packed[pos] = mydat[jj];
        }
    }
}

// ---------------- P4: per-coarse-bucket fine sort -> off[] + srcs[] ----------------
__global__ __launch_bounds__(1024) void fsort_kernel(const int* __restrict__ gstart,
                                                     const uint* __restrict__ packed,
                                                     int* __restrict__ off,
                                                     int* __restrict__ srcs) {
    __shared__ int hist[NSB];
    __shared__ int scn[NSB];
    __shared__ int h2[1024];
    const int b = blockIdx.x;
    const int t = threadIdx.x;
    const int s = gstart[b], e = gstart[b + 1];

    for (int i = t; i < NSB; i += 1024) hist[i] = 0;
    __syncthreads();
    for (int i = s + t; i < e; i += 1024)
        atomicAdd(&hist[(packed[i] >> 16) & 0x7FF], 1);
    __syncthreads();
    const int a0 = hist[2 * t], a1 = hist[2 * t + 1];
    h2[t] = a0 + a1;
    __syncthreads();
    for (int d = 1; d < 1024; d <<= 1) {
        int u = (t >= d) ? h2[t - d] : 0;
        __syncthreads();
        h2[t] += u;
        __syncthreads();
    }
    const int base = h2[t] - (a0 + a1);
    scn[2 * t] = base;
    scn[2 * t + 1] = base + a0;
    __syncthreads();
    const int gsubbase = b << 11;
    for (int i = t; i < NSB; i += 1024) {
        const int g = gsubbase + i;
        if (g < NB) off[g] = s + scn[i];
    }
    if (b == NCB - 1 && t == 0) off[NB] = EE;
    __syncthreads();
    for (int i = s + t; i < e; i += 1024) {
        const uint k = packed[i];
        const int pos = atomicAdd(&scn[(k >> 16) & 0x7FF], 1);
        srcs[s + pos] = (int)(k & 0xFFFF);
    }
}

// ---------------- x fp32 -> bf16 ----------------
__global__ __launch_bounds__(256) void cvt_x_kernel(const float* __restrict__ x,
                                                    ushort* __restrict__ xb) {
    const int tid = blockIdx.x * blockDim.x + threadIdx.x;
    const size_t i = (size_t)tid * 8;
    const float4 v0 = *reinterpret_cast<const float4*>(x + i);
    const float4 v1 = *reinterpret_cast<const float4*>(x + i + 4);
    uint4 o;
    o.x = (uint)f2bf(v0.x) | ((uint)f2bf(v0.y) << 16);
    o.y = (uint)f2bf(v0.z) | ((uint)f2bf(v0.w) << 16);
    o.z = (uint)f2bf(v1.x) | ((uint)f2bf(v1.y) << 16);
    o.w = (uint)f2bf(v1.z) | ((uint)f2bf(v1.w) << 16);
    *reinterpret_cast<uint4*>(xb + i) = o;
}

// ---------------- weights -> Bt[n][k] bf16, k = [root(128) | W(1024)] ----------------
__global__ __launch_bounds__(256) void prep_w_kernel(const float* __restrict__ root1,
                                                     const float* __restrict__ W1,
                                                     const float* __restrict__ root2,
                                                     const float* __restrict__ W2,
                                                     ushort* __restrict__ Bt1,
                                                     ushort* __restrict__ Bt2) {
    const float* root = blockIdx.y ? root2 : root1;
    const float* W    = blockIdx.y ? W2 : W1;
    ushort* Bt        = blockIdx.y ? Bt2 : Bt1;
    const int n = blockIdx.x;
    for (int k = threadIdx.x; k < 1152; k += 256) {
        float v = (k < 128) ? root[(size_t)k * 128 + n]
                            : W[(size_t)(k - 128) * 128 + n];
        Bt[(size_t)n * 1152 + k] = f2bf(v);
    }
}

// ---------------- FUSED agg+GEMM: h = relu(bias + [xb | mean_r(xb)] @ Bt^T) ----------------
// Block: 256 thr = 4 waves (2x2), tile 64(M) x 128(N), BK=128, mfma 32x32x16.
// LDS: A 64x256B (16KB, chunk swizzle c^(row&7)) | B 128x256B (32KB, same swizzle).
// kt=0: A=xb rows via global_load_lds (pre-swizzled source, linear dest).
// kt=1..8 (rel r=kt-1): A produced by gather: lane(node i=t>>2, j=t&3) owns
// 64B of the row -> 32 fp32 accums -> mean -> bf16 -> 4 swizzled ds_write_b128.
// B staged async (global_load_lds) BEFORE the gather so its latency hides.
__global__ __launch_bounds__(256) void gemm_fused(const ushort* __restrict__ feat,
                                                  const int* __restrict__ off,
                                                  const int* __restrict__ srcs,
                                                  const ushort* __restrict__ Bt,
                                                  const float* __restrict__ bias,
                                                  ushort* __restrict__ hout) {
    __shared__ __align__(16) uint8_t smem[49152];   // A[0,16384) | B[16384,49152)
    const int t = threadIdx.x;
    const int lane = t & 63;
    const int w = t >> 6;
    const int wr = w >> 1, wc = w & 1;
    const int n0 = blockIdx.x * 64;
    const int l31 = lane & 31;
    const int lhalf = lane >> 5;

    f32x16 acc0, acc1;
#pragma unroll
    for (int r = 0; r < 16; ++r) { acc0[r] = 0.f; acc1[r] = 0.f; }

    // fragment read constants (256B rows, chunk swizzle ^(row&7) on 16B chunks)
    const int rA = wr * 32 + l31;
    const int aoff = rA * 256, aswz = (rA & 7) << 4;
    const int nB0 = wc * 64 + l31, nB1 = nB0 + 32;
    const int boff0 = 16384 + nB0 * 256, bswz0 = (nB0 & 7) << 4;
    const int boff1 = 16384 + nB1 * 256, bswz1 = (nB1 & 7) << 4;
    const int ckb = lhalf << 4;

    // gather assignment: node i = t>>2 (0..63), j = t&3 (64B sub-row)
    const int gi = t >> 2, gj = t & 3;
    const int gnode = min(n0 + gi, NN - 1);
    int offs[9];
#pragma unroll
    for (int r = 0; r < 9; ++r) offs[r] = off[gnode * 8 + r];

    // staging lane mapping: row-in-instr = lane>>4 (4 rows x 256B = 1KB/instr),
    // chunk = lane&15; source pre-swizzled with ^(row&7).
    const int srow = lane >> 4;
    const int schunk = lane & 15;

    const uint8_t* feat8 = (const uint8_t*)feat;
    const uint8_t* Bt8   = (const uint8_t*)Bt;

    auto STAGE_B = [&](int kt) {                     // 8 instrs/wave, 32 rows
#pragma unroll
        for (int jj = 0; jj < 8; ++jj) {
            const int n = w * 32 + jj * 4 + srow;    // 0..127 (local == global col)
            stage16(Bt8 + (size_t)n * 2304 + kt * 256 + ((schunk ^ (n & 7)) << 4),
                    smem + 16384 + (w * 32 + jj * 4) * 256 + (size_t)0 /*+lane*16 by HW*/);
        }
    };
    auto STAGE_A0 = [&]() {                          // 4 instrs/wave, 16 rows
#pragma unroll
        for (int jj = 0; jj < 4; ++jj) {
            const int lr = w * 16 + jj * 4 + srow;   // local row 0..63
            const int gr = min(n0 + lr, NN - 1);
            stage16(feat8 + (size_t)gr * 256 + ((schunk ^ (lr & 7)) << 4),
                    smem + (w * 16 + jj * 4) * 256);
        }
    };

    auto COMPUTE = [&]() {
#pragma unroll
        for (int kb = 0; kb < 8; ++kb) {
            const int cb = kb * 32 + ckb;
            const bf16x8 af = *reinterpret_cast<const bf16x8*>(smem + aoff  + (cb ^ aswz));
            const bf16x8 b0 = *reinterpret_cast<const bf16x8*>(smem + boff0 + (cb ^ bswz0));
            const bf16x8 b1 = *reinterpret_cast<const bf16x8*>(smem + boff1 + (cb ^ bswz1));
            acc0 = __builtin_amdgcn_mfma_f32_32x32x16_bf16(af, b0, acc0, 0, 0, 0);
            acc1 = __builtin_amdgcn_mfma_f32_32x32x16_bf16(af, b1, acc1, 0, 0, 0);
        }
    };

    // ---- tile 0: root term (A = xb rows) ----
    STAGE_A0();
    STAGE_B(0);
    __syncthreads();                  // vmcnt(0) drain: A+B ready
    COMPUTE();
    __syncthreads();                  // reads done; buffers free

    // ---- tiles 1..8: relation r = kt-1, A produced by gather ----
#pragma unroll
    for (int r = 0; r < 8; ++r) {
        STAGE_B(r + 1);               // async B loads fly under the gather
        {
            const int s = offs[r], e = offs[r + 1];
            float a[32];
#pragma unroll
            for (int k = 0; k < 32; ++k) a[k] = 0.f;
            int p = (s < e) ? srcs[s] : 0;
            for (int i = s; i < e; ++i) {
                const int pn = (i + 1 < e) ? srcs[i + 1] : 0;   // prefetch next src
                const uint4* rp = reinterpret_cast<const uint4*>(
                    feat8 + (size_t)p * 256 + (gj << 6));
                const uint4 q0 = rp[0], q1 = rp[1], q2 = rp[2], q3 = rp[3];
                const uint u[16] = { q0.x,q0.y,q0.z,q0.w, q1.x,q1.y,q1.z,q1.w,
                                     q2.x,q2.y,q2.z,q2.w, q3.x,q3.y,q3.z,q3.w };
#pragma unroll
                for (int m = 0; m < 16; ++m) {
                    a[2 * m]     += bflo(u[m]);
                    a[2 * m + 1] += bfhi(u[m]);
                }
                p = pn;
            }
            const float inv = 1.0f / (float)max(e - s, 1);
            uint o[16];
#pragma unroll
            for (int m = 0; m < 16; ++m)
                o[m] = (uint)f2bf(a[2 * m] * inv) | ((uint)f2bf(a[2 * m + 1] * inv) << 16);
#pragma unroll
            for (int m = 0; m < 4; ++m) {
                const int chunk = (4 * gj + m) ^ (gi & 7);
                *reinterpret_cast<uint4*>(smem + gi * 256 + chunk * 16) =
                    make_uint4(o[4 * m], o[4 * m + 1], o[4 * m + 2], o[4 * m + 3]);
            }
        }
        __syncthreads();              // drains vmcnt (B) + lgkm (A ds_writes)
        COMPUTE();
        __syncthreads();
    }

    // epilogue: 32x32 C/D layout: col = lane&31, row = (reg&3)+8*(reg>>2)+4*(lane>>5)
#pragma unroll
    for (int ni = 0; ni < 2; ++ni) {
        const int col = wc * 64 + ni * 32 + l31;
        const float bv = bias[col];
        const f32x16& a = ni ? acc1 : acc0;
#pragma unroll
        for (int reg = 0; reg < 16; ++reg) {
            const int row = n0 + wr * 32 + 4 * lhalf + (reg & 3) + 8 * (reg >> 2);
            if (row < NN) {
                const float v = fmaxf(a[reg] + bv, 0.f);
                hout[(size_t)row * 128 + col] = f2bf(v);
            }
        }
    }
}

// ---------------- head: out[n] = h2[n] . Wout + bout ----------------
__global__ __launch_bounds__(256) void out_kernel(const ushort* __restrict__ h2,
                                                  const float* __restrict__ Wout,
                                                  const float* __restrict__ bout,
                                                  float* __restrict__ outp) {
    const int wid = (blockIdx.x * blockDim.x + threadIdx.x) >> 6;
    if (wid >= NN) return;
    const int lane = threadIdx.x & 63;
    const uint v = *reinterpret_cast<const uint*>(h2 + (size_t)wid * 128 + (lane << 1));
    const float2 ww = *reinterpret_cast<const float2*>(Wout + (lane << 1));
    float s = fmaf(bflo(v), ww.x, bfhi(v) * ww.y);
#pragma unroll
    for (int d = 32; d > 0; d >>= 1) s += __shfl_down(s, d, 64);
    if (lane == 0) outp[wid] = s + bout[0];
}

extern "C" void kernel_launch(void* const* d_in, const int* in_sizes, int n_in,
                              void* d_out, int out_size, void* d_ws, size_t ws_size,
                              hipStream_t stream) {
    const float* x     = (const float*)d_in[0];
    const int*   eidx  = (const int*)  d_in[1];
    const int*   etype = (const int*)  d_in[2];
    const float* W1    = (const float*)d_in[3];
    const float* root1 = (const float*)d_in[4];
    const float* b1    = (const float*)d_in[5];
    const float* W2    = (const float*)d_in[6];
    const float* root2 = (const float*)d_in[7];
    const float* b2    = (const float*)d_in[8];
    const float* Wout  = (const float*)d_in[9];
    const float* bout  = (const float*)d_in[10];
    float* out = (float*)d_out;

    const int* src = eidx;
    const int* dst = eidx + EE;

    char* ws = (char*)d_ws;
    size_t pos = 0;
    auto take = [&](size_t bytes) {
        char* p = ws + pos;
        pos = (pos + bytes + 255) & ~(size_t)255;
        return p;
    };
    int*    ghist  = (int*)   take((size_t)NCB * 4);
    int*    gstart = (int*)   take((size_t)(NCB + 1) * 4);
    int*    gcur   = (int*)   take((size_t)NCB * 4);
    uint*   packed = (uint*)  take((size_t)EE * 4);
    int*    off    = (int*)   take((size_t)(NB + 1) * 4);
    int*    srcs   = (int*)   take((size_t)EE * 4);
    ushort* xb     = (ushort*)take((size_t)NN * 128 * 2);
    ushort* h1     = (ushort*)take((size_t)NN * 128 * 2);
    ushort* h2     = (ushort*)take((size_t)NN * 128 * 2);
    ushort* Bt1    = (ushort*)take((size_t)128 * 1152 * 2);
    ushort* Bt2    = (ushort*)take((size_t)128 * 1152 * 2);
    (void)ws_size; (void)n_in; (void)in_sizes; (void)out_size;

    const int wblocks = (NN + 3) / 4;               // 12500 wave-per-node (head)
    const int gblocks = (NN + 63) / 64;             // 782 fused GEMM tiles

    hipMemsetAsync(ghist, 0, (size_t)NCB * 4, stream);
    chist_kernel<<<PBLK, 1024, 0, stream>>>(dst, ghist);
    cscan_kernel<<<1, 256, 0, stream>>>(ghist, gstart, gcur);
    cpart_kernel<<<PBLK, 1024, 0, stream>>>(src, dst, etype, gcur, packed);
    fsort_kernel<<<NCB, 1024, 0, stream>>>(gstart, packed, off, srcs);
    prep_w_kernel<<<dim3(128, 2), 256, 0, stream>>>(root1, W1, root2, W2, Bt1, Bt2);
    cvt_x_kernel <<<3125, 256, 0, stream>>>(x, xb);

    // layer 1 (fused agg+gemm)
    gemm_fused<<<gblocks, 256, 0, stream>>>(xb, off, srcs, Bt1, b1, h1);
    // layer 2
    gemm_fused<<<gblocks, 256, 0, stream>>>(h1, off, srcs, Bt2, b2, h2);
    // head
    out_kernel<<<wblocks, 256, 0, stream>>>(h2, Wout, bout, out);
}